// Round 18
// baseline (411.514 us; speedup 1.0000x reference)
//
#include <hip/hip_runtime.h>

// ---------------------------------------------------------------------------
// GraphElementNetwork forward, bucketed path v17 (r17 + enc/chist fusion):
//  - k_encchist: node-encoder MLP (VALU-bound, ~15us) fused into the dst
//    histogram (memory-bound, VALUBusy ~1%) — independent phases, enc VALU
//    hides in chist's memory-stall shadow (wave-level pipe overlap).
//  - everything else = r17/r16 best (378us): shift=9, NHB=512, G<=16,
//    passB h1loc+4-edge+prefetch (102us floor over 7 variants), e2 in-place
//    into payA.y, passC single-stream, exp(dist) computed in scatter,
//    weights wave-uniform scalar loads.
// ---------------------------------------------------------------------------

#define NHB 512   // histogram / scatter blocks (2 per CU)

typedef int   iv4 __attribute__((ext_vector_type(4)));
typedef float fv4 __attribute__((ext_vector_type(4)));
typedef float fv2 __attribute__((ext_vector_type(2)));

#if __has_builtin(__builtin_elementwise_fma)
#define FMA2(a, b, c) __builtin_elementwise_fma((a), (b), (c))
#else
static __device__ __forceinline__ fv2 FMA2(fv2 a, fv2 b, fv2 c) {
    fv2 r; r.x = fmaf(a.x, b.x, c.x); r.y = fmaf(a.y, b.y, c.y); return r;
}
#endif
#if __has_builtin(__builtin_elementwise_max)
#define MAX2(a, b) __builtin_elementwise_max((a), (b))
#else
static __device__ __forceinline__ fv2 MAX2(fv2 a, fv2 b) {
    fv2 r; r.x = fmaxf(a.x, b.x); r.y = fmaxf(a.y, b.y); return r;
}
#endif

// ================= fused node-encoder + dst histogram ======================
// Phase 1 (VALU): H0[i] = encMLP(node_feat[i]) for grid-stride i.
// Phase 2 (memory): per-block LDS histogram of dst>>shift.
// Independent data; waves naturally stagger so enc FMAs fill chist's
// memory-stall shadow.
__global__ void __launch_bounds__(1024) k_encchist(
    const float* __restrict__ X, const float* __restrict__ W1,
    const float* __restrict__ B1, const float* __restrict__ W2,
    const float* __restrict__ B2, float* __restrict__ H0, int n,
    const int* __restrict__ DST, int* __restrict__ hist,
    int e, int nbkt, int shift, int epb)
{
    __shared__ float4 w1s[2048];
    __shared__ int lh[512];
    for (int t = threadIdx.x; t < 2048; t += blockDim.x)
        w1s[t] = reinterpret_cast<const float4*>(W1)[t];
    for (int c = threadIdx.x; c < 512; c += blockDim.x) lh[c] = 0;
    __syncthreads();

    // ---- enc phase (grid-stride over nodes) ----
    for (int i = blockIdx.x * blockDim.x + threadIdx.x; i < n;
         i += gridDim.x * blockDim.x) {
        const float4* xp = reinterpret_cast<const float4*>(X) + (size_t)i * 32;
        float acc[64];
        #pragma unroll
        for (int j = 0; j < 64; ++j) acc[j] = B1[j];
        for (int k4 = 0; k4 < 32; ++k4) {
            float4 xv = xp[k4];
            #pragma unroll
            for (int kk = 0; kk < 4; ++kk) {
                float x = (&xv.x)[kk];
                const float4* wrow = &w1s[(k4 * 4 + kk) * 16];
                #pragma unroll
                for (int j4 = 0; j4 < 16; ++j4) {
                    float4 w = wrow[j4];
                    acc[j4*4+0] = fmaf(x, w.x, acc[j4*4+0]);
                    acc[j4*4+1] = fmaf(x, w.y, acc[j4*4+1]);
                    acc[j4*4+2] = fmaf(x, w.z, acc[j4*4+2]);
                    acc[j4*4+3] = fmaf(x, w.w, acc[j4*4+3]);
                }
            }
        }
        float o = B2[0];
        #pragma unroll
        for (int j = 0; j < 64; ++j)
            o = fmaf(fmaxf(acc[j], 0.f), W2[j], o);
        H0[i] = fmaxf(o, 0.f);
    }

    // ---- chist phase (lh zeroed before the barrier above) ----
    int b = blockIdx.x;
    int i0 = b * epb, i1 = min(i0 + epb, e);
    if (i0 < i1) {
        int nq = (i1 - i0) >> 2;
        const iv4* D4 = reinterpret_cast<const iv4*>(DST + i0);
        for (int q = threadIdx.x; q < nq; q += blockDim.x) {
            iv4 d = __builtin_nontemporal_load(D4 + q);
            atomicAdd(&lh[d.x >> shift], 1);
            atomicAdd(&lh[d.y >> shift], 1);
            atomicAdd(&lh[d.z >> shift], 1);
            atomicAdd(&lh[d.w >> shift], 1);
        }
        for (int i = i0 + 4 * nq + threadIdx.x; i < i1; i += blockDim.x)
            atomicAdd(&lh[DST[i] >> shift], 1);
    }
    __syncthreads();
    for (int c = threadIdx.x; c < nbkt; c += blockDim.x)
        hist[(size_t)c * NHB + b] = lh[c];
}

// exclusive scan of each bucket's NHB=512 per-block counts (2 elems/thread)
__global__ void __launch_bounds__(256) k_scanA(
    int* __restrict__ hist, int* __restrict__ bktCnt)
{
    int c = blockIdx.x;
    int* row = hist + (size_t)c * NHB;
    __shared__ int part[256];
    int t = threadIdx.x;
    int a = row[2 * t];
    int bv = row[2 * t + 1];
    part[t] = a + bv;
    __syncthreads();
    for (int off = 1; off < 256; off <<= 1) {
        int x = 0;
        if (t >= off) x = part[t - off];
        __syncthreads();
        part[t] += x;
        __syncthreads();
    }
    if (t == 255) bktCnt[c] = part[255];
    int run = (t == 0) ? 0 : part[t - 1];
    row[2 * t] = run;
    row[2 * t + 1] = run + a;
}

__global__ void __launch_bounds__(256) k_scanB(
    const int* __restrict__ bktCnt, int* __restrict__ base, int nbkt, int e)
{
    __shared__ int part[256];
    int t = threadIdx.x;
    int v[4];
    int sum = 0;
    #pragma unroll
    for (int u = 0; u < 4; ++u) {
        int idx = t * 4 + u;
        v[u] = (idx < nbkt) ? bktCnt[idx] : 0;
        sum += v[u];
    }
    part[t] = sum;
    __syncthreads();
    for (int off = 1; off < 256; off <<= 1) {
        int x = 0;
        if (t >= off) x = part[t - off];
        __syncthreads();
        part[t] += x;
        __syncthreads();
    }
    int run = (t == 0) ? 0 : part[t - 1];
    #pragma unroll
    for (int u = 0; u < 4; ++u) {
        int idx = t * 4 + u;
        if (idx < nbkt) base[idx] = run;
        run += v[u];
    }
    if (t == 0) base[nbkt] = e;
}

// scatter: payA[pos] = (sd, exp(dist)); ef_s[pos] = ef
__global__ void __launch_bounds__(1024) k_scatter(
    const int* __restrict__ DST, const int* __restrict__ SRC,
    const float* __restrict__ DIST, const float* __restrict__ EF,
    const int* __restrict__ hist, const int* __restrict__ base,
    float2* __restrict__ payA, float* __restrict__ ef_s,
    int e, int nbkt, int shift, int epb)
{
    __shared__ int loff[512];
    int b = blockIdx.x;
    for (int c = threadIdx.x; c < nbkt; c += blockDim.x)
        loff[c] = base[c] + hist[(size_t)c * NHB + b];
    __syncthreads();
    int i0 = b * epb, i1 = min(i0 + epb, e);
    if (i0 >= i1) return;
    int mask = (1 << shift) - 1;
    int nq = (i1 - i0) >> 2;
    const iv4* D4 = reinterpret_cast<const iv4*>(DST + i0);
    const iv4* S4 = reinterpret_cast<const iv4*>(SRC + i0);
    const fv4* T4 = reinterpret_cast<const fv4*>(DIST + i0);
    const fv4* F4 = reinterpret_cast<const fv4*>(EF + i0);
    for (int q = threadIdx.x; q < nq; q += blockDim.x) {
        iv4 dv = __builtin_nontemporal_load(D4 + q);
        iv4 sv = __builtin_nontemporal_load(S4 + q);
        fv4 tv = __builtin_nontemporal_load(T4 + q);
        fv4 fv = __builtin_nontemporal_load(F4 + q);
        #pragma unroll
        for (int u = 0; u < 4; ++u) {
            int d = dv[u];
            int c = d >> shift;
            int pos = atomicAdd(&loff[c], 1);
            int sd = (sv[u] << shift) | (d & mask);
            payA[pos] = make_float2(__int_as_float(sd), __expf(tv[u]));
            ef_s[pos] = fv[u];
        }
    }
    for (int i = i0 + 4 * nq + threadIdx.x; i < i1; i += blockDim.x) {
        int d = DST[i];
        int c = d >> shift;
        int pos = atomicAdd(&loff[c], 1);
        int sd = (SRC[i] << shift) | (d & mask);
        payA[pos] = make_float2(__int_as_float(sd), __expf(DIST[i]));
        ef_s[pos] = EF[i];
    }
}

// =============== node encoder (fallback path only) =========================

__global__ void __launch_bounds__(256) k_enc(
    const float* __restrict__ X, const float* __restrict__ W1,
    const float* __restrict__ B1, const float* __restrict__ W2,
    const float* __restrict__ B2, float* __restrict__ H0, int n)
{
    __shared__ float4 w1s[2048];
    for (int t = threadIdx.x; t < 2048; t += blockDim.x)
        w1s[t] = reinterpret_cast<const float4*>(W1)[t];
    __syncthreads();

    int i = blockIdx.x * blockDim.x + threadIdx.x;
    if (i >= n) return;

    const float4* xp = reinterpret_cast<const float4*>(X) + (size_t)i * 32;

    float acc[64];
    #pragma unroll
    for (int j = 0; j < 64; ++j) acc[j] = B1[j];

    for (int k4 = 0; k4 < 32; ++k4) {
        float4 xv = xp[k4];
        #pragma unroll
        for (int kk = 0; kk < 4; ++kk) {
            float x = (&xv.x)[kk];
            const float4* wrow = &w1s[(k4 * 4 + kk) * 16];
            #pragma unroll
            for (int j4 = 0; j4 < 16; ++j4) {
                float4 w = wrow[j4];
                acc[j4*4+0] = fmaf(x, w.x, acc[j4*4+0]);
                acc[j4*4+1] = fmaf(x, w.y, acc[j4*4+1]);
                acc[j4*4+2] = fmaf(x, w.z, acc[j4*4+2]);
                acc[j4*4+3] = fmaf(x, w.w, acc[j4*4+3]);
            }
        }
    }
    float o = B2[0];
    #pragma unroll
    for (int j = 0; j < 64; ++j)
        o = fmaf(fmaxf(acc[j], 0.f), W2[j], o);
    H0[i] = fmaxf(o, 0.f);
}

// ==================== bucketed edge passes (G-split) =======================
// partial layout: p[((c*G + g) << shift) + t]

__global__ void __launch_bounds__(256) k_passA(
    const float2* __restrict__ payA, const float* __restrict__ H0,
    const int* __restrict__ base,
    float* __restrict__ pSum, float* __restrict__ pNum, int shift, int G)
{
    __shared__ float lsum[512], lnum[512];
    int c = blockIdx.x / G, g = blockIdx.x % G;
    int bw = 1 << shift, mask = bw - 1;
    for (int t = threadIdx.x; t < bw; t += blockDim.x) { lsum[t] = 0.f; lnum[t] = 0.f; }
    __syncthreads();
    int b0 = base[c], len = base[c + 1] - b0;
    int i0 = b0 + (int)(((long long)len * g) / G);
    int i1 = b0 + (int)(((long long)len * (g + 1)) / G);
    const int T = blockDim.x;
    for (int i = i0 + (int)threadIdx.x; i < i1; i += 4 * T) {
        fv2 p[4]; bool v[4]; int sd[4]; float h[4];
        #pragma unroll
        for (int u = 0; u < 4; ++u) {
            int j = i + u * T;
            v[u] = j < i1;
            p[u].x = 0.f; p[u].y = 0.f;
            if (v[u]) p[u] = __builtin_nontemporal_load(
                          reinterpret_cast<const fv2*>(payA) + j);
        }
        #pragma unroll
        for (int u = 0; u < 4; ++u) {
            sd[u] = __float_as_int(p[u].x);
            h[u] = v[u] ? H0[sd[u] >> shift] : 0.f;
        }
        #pragma unroll
        for (int u = 0; u < 4; ++u) {
            if (v[u]) {
                atomicAdd(&lsum[sd[u] & mask], p[u].y);          // exp(dist)
                atomicAdd(&lnum[sd[u] & mask], p[u].y * h[u]);
            }
        }
    }
    __syncthreads();
    size_t po = (size_t)blockIdx.x << shift;
    for (int t = threadIdx.x; t < bw; t += blockDim.x) {
        pSum[po + t] = lsum[t];
        pNum[po + t] = lnum[t];
    }
}

__global__ void __launch_bounds__(256) k_finA(
    const float* __restrict__ pSum, const float* __restrict__ pNum,
    float* __restrict__ H1, int shift, int n, int G)
{
    int d = blockIdx.x * blockDim.x + threadIdx.x;
    if (d >= n) return;
    int c = d >> shift, t = d & ((1 << shift) - 1);
    size_t b = (size_t)c * G << shift;
    int bw = 1 << shift;
    float s = 0.f, m = 0.f;
    for (int g = 0; g < G; ++g) {
        s += pSum[b + (size_t)g * bw + t];
        m += pNum[b + (size_t)g * bw + t];
    }
    H1[d] = (s != 0.f) ? m / s : 0.f;
}

// passB main (r10 structure): edge MLP; writes e2 into payA[j].y (in-place,
// exp(dist) is dead after passA); partial agg/s2 into LDS bins.
__global__ void __launch_bounds__(256) k_passB(
    float2* __restrict__ payA, const float* __restrict__ ef_s,
    const float* __restrict__ H1,
    const float* __restrict__ W1, const float* __restrict__ B1,
    const float* __restrict__ W2, const float* __restrict__ B2,
    const int* __restrict__ base,
    float* __restrict__ pAgg, float* __restrict__ pS2, int shift, int n, int G)
{
    __shared__ float h1loc[512], lagg[512], ls2[512];
    const fv2 ZERO2 = {0.f, 0.f};
    int bw = 1 << shift, mask = bw - 1;
    int c = blockIdx.x / G, g = blockIdx.x % G;
    int d0 = c << shift;
    for (int t = threadIdx.x; t < bw; t += blockDim.x) {
        int d = d0 + t;
        h1loc[t] = (d < n) ? H1[d] : 0.f;
        lagg[t] = 0.f;
        ls2[t] = 0.f;
    }
    __syncthreads();
    const float b2 = B2[0];
    int b0 = base[c], len = base[c + 1] - b0;
    int i0 = b0 + (int)(((long long)len * g) / G);
    int i1 = b0 + (int)(((long long)len * (g + 1)) / G);
    const int T = blockDim.x;

    int i = i0 + (int)threadIdx.x;
    fv2 pa[4]; float xf[4];
    #pragma unroll
    for (int u = 0; u < 4; ++u) {
        int j = i + u * T;
        pa[u] = ZERO2; xf[u] = 0.f;
        if (j < i1) {
            pa[u] = __builtin_nontemporal_load(
                reinterpret_cast<const fv2*>(payA) + j);
            xf[u] = __builtin_nontemporal_load(ef_s + j);
        }
    }
    float* payF = reinterpret_cast<float*>(payA);
    while (i < i1) {
        int inext = i + 4 * T;
        // prefetch next chunk BEFORE the store/atomic phase of this chunk
        fv2 pb[4]; float xg[4];
        #pragma unroll
        for (int u = 0; u < 4; ++u) {
            int j = inext + u * T;
            pb[u] = ZERO2; xg[u] = 0.f;
            if (j < i1) {
                pb[u] = __builtin_nontemporal_load(
                    reinterpret_cast<const fv2*>(payA) + j);
                xg[u] = __builtin_nontemporal_load(ef_s + j);
            }
        }
        // gathers + packed MLP
        fv2 x0v[4], hsv[4], hdv[4], o2[4];
        int lo[4];
        #pragma unroll
        for (int u = 0; u < 4; ++u) {
            int sd = __float_as_int(pa[u].x);
            lo[u] = sd & mask;
            float hs = H1[sd >> shift];
            float hd = h1loc[lo[u]];
            fv2 xt; xt.x = xf[u]; xt.y = xf[u];
            x0v[u] = xt;
            fv2 ht; ht.x = hs; ht.y = hs;
            hsv[u] = ht;
            fv2 dt; dt.x = hd; dt.y = hd;
            hdv[u] = dt;
            o2[u] = ZERO2;
        }
        #pragma unroll 4
        for (int j = 0; j < 64; j += 2) {
            fv2 aj = *reinterpret_cast<const fv2*>(W1 + j);
            fv2 bj = *reinterpret_cast<const fv2*>(W1 + 64 + j);
            fv2 cj = *reinterpret_cast<const fv2*>(W1 + 128 + j);
            fv2 dj = *reinterpret_cast<const fv2*>(B1 + j);
            fv2 vj = *reinterpret_cast<const fv2*>(W2 + j);
            #pragma unroll
            for (int u = 0; u < 4; ++u) {
                fv2 t = FMA2(x0v[u], aj,
                         FMA2(hsv[u], bj, FMA2(hdv[u], cj, dj)));
                t = MAX2(t, ZERO2);
                o2[u] = FMA2(t, vj, o2[u]);
            }
        }
        #pragma unroll
        for (int u = 0; u < 4; ++u) {
            int j = i + u * T;
            if (j < i1) {
                float eh = fmaxf(o2[u].x + o2[u].y + b2, 0.f);
                float ex = __expf(eh);
                payF[2 * j + 1] = ex;   // e2 -> payA[j].y
                atomicAdd(&lagg[lo[u]], eh);
                atomicAdd(&ls2[lo[u]], ex);
            }
        }
        i = inext;
        #pragma unroll
        for (int u = 0; u < 4; ++u) { pa[u] = pb[u]; xf[u] = xg[u]; }
    }
    __syncthreads();
    size_t po = (size_t)blockIdx.x << shift;
    for (int t = threadIdx.x; t < bw; t += blockDim.x) {
        pAgg[po + t] = lagg[t];
        pS2[po + t] = ls2[t];
    }
}

// finB: sum partials; H2 = nuMLP(agg, h1); S2
__global__ void __launch_bounds__(256) k_finB(
    const float* __restrict__ pAgg, const float* __restrict__ pS2,
    const float* __restrict__ H1,
    const float* __restrict__ NW1, const float* __restrict__ NB1,
    const float* __restrict__ NW2, const float* __restrict__ NB2,
    float* __restrict__ H2, float* __restrict__ S2, int shift, int n, int G)
{
    int d = blockIdx.x * blockDim.x + threadIdx.x;
    if (d >= n) return;
    int c = d >> shift, t = d & ((1 << shift) - 1);
    size_t b = (size_t)c * G << shift;
    int bw = 1 << shift;
    float agg = 0.f, s2 = 0.f;
    for (int g = 0; g < G; ++g) {
        agg += pAgg[b + (size_t)g * bw + t];
        s2  += pS2[b + (size_t)g * bw + t];
    }
    float xh = H1[d];
    float o = NB2[0];
    #pragma unroll 4
    for (int j = 0; j < 64; ++j) {
        float a = fmaf(agg, NW1[j], fmaf(xh, NW1[64 + j], NB1[j]));
        o = fmaf(fmaxf(a, 0.f), NW2[j], o);
    }
    H2[d] = fmaxf(o, 0.f);
    S2[d] = s2;
}

// passC main: partial num2. Single contiguous stream: payA[j] = (sd, e2).
__global__ void __launch_bounds__(256) k_passC(
    const float2* __restrict__ payA,
    const float* __restrict__ H2, const int* __restrict__ base,
    float* __restrict__ pNum, int shift, int G)
{
    __shared__ float lnum[512];
    int c = blockIdx.x / G, g = blockIdx.x % G;
    int bw = 1 << shift, mask = bw - 1;
    for (int t = threadIdx.x; t < bw; t += blockDim.x) lnum[t] = 0.f;
    __syncthreads();
    int b0 = base[c], len = base[c + 1] - b0;
    int i0 = b0 + (int)(((long long)len * g) / G);
    int i1 = b0 + (int)(((long long)len * (g + 1)) / G);
    const int T = blockDim.x;
    for (int i = i0 + (int)threadIdx.x; i < i1; i += 4 * T) {
        fv2 p[4]; bool v[4]; int sd[4]; float h[4];
        #pragma unroll
        for (int u = 0; u < 4; ++u) {
            int j = i + u * T;
            v[u] = j < i1;
            p[u].x = 0.f; p[u].y = 0.f;
            if (v[u]) p[u] = __builtin_nontemporal_load(
                          reinterpret_cast<const fv2*>(payA) + j);
        }
        #pragma unroll
        for (int u = 0; u < 4; ++u) {
            sd[u] = __float_as_int(p[u].x);
            h[u] = v[u] ? H2[sd[u] >> shift] : 0.f;
        }
        #pragma unroll
        for (int u = 0; u < 4; ++u) {
            if (v[u]) atomicAdd(&lnum[sd[u] & mask], p[u].y * h[u]);
        }
    }
    __syncthreads();
    size_t po = (size_t)blockIdx.x << shift;
    for (int t = threadIdx.x; t < bw; t += blockDim.x)
        pNum[po + t] = lnum[t];
}

// finC: sum partials; OUT = decMLP(num2/s2)
__global__ void __launch_bounds__(256) k_finC(
    const float* __restrict__ pNum, const float* __restrict__ S2,
    const float* __restrict__ W1, const float* __restrict__ B1,
    const float* __restrict__ W2, const float* __restrict__ B2,
    float* __restrict__ OUT, int shift, int n, int G)
{
    int d = blockIdx.x * blockDim.x + threadIdx.x;
    if (d >= n) return;
    int c = d >> shift, t = d & ((1 << shift) - 1);
    size_t b = (size_t)c * G << shift;
    int bw = 1 << shift;
    float m = 0.f;
    for (int g = 0; g < G; ++g) m += pNum[b + (size_t)g * bw + t];
    float s = S2[d];
    float x = (s != 0.f) ? m / s : 0.f;
    float o = B2[0];
    #pragma unroll 4
    for (int j = 0; j < 64; ++j) {
        float a = fmaf(x, W1[j], B1[j]);
        o = fmaf(fmaxf(a, 0.f), W2[j], o);
    }
    OUT[d] = fmaxf(o, 0.f);
}

// ===================== fallback (atomic path) ==============================

__device__ __forceinline__ void atomAddF(float* p, float v) { unsafeAtomicAdd(p, v); }

__global__ void k_zero(float* __restrict__ p, int n) {
    int i = blockIdx.x * blockDim.x + threadIdx.x;
    if (i < n) p[i] = 0.f;
}

__global__ void __launch_bounds__(256) k_agg1(
    const float* __restrict__ DIST, const int* __restrict__ SRC,
    const int* __restrict__ DST, const float* __restrict__ H0,
    float* __restrict__ S1, float* __restrict__ NUM1, int e)
{
    int i = blockIdx.x * blockDim.x + threadIdx.x;
    if (i >= e) return;
    float ev = __expf(DIST[i]);
    atomAddF(&S1[DST[i]], ev);
    atomAddF(&NUM1[DST[i]], ev * H0[SRC[i]]);
}

__global__ void k_div(const float* __restrict__ NUM, const float* __restrict__ S,
                      float* __restrict__ H, int n) {
    int i = blockIdx.x * blockDim.x + threadIdx.x;
    if (i < n) {
        float s = S[i];
        H[i] = (s != 0.f) ? NUM[i] / s : 0.f;
    }
}

__global__ void __launch_bounds__(256) k_edgeF(
    const float* __restrict__ EF, const int* __restrict__ SRC,
    const int* __restrict__ DST, const float* __restrict__ H1,
    const float* __restrict__ W1, const float* __restrict__ B1,
    const float* __restrict__ W2, const float* __restrict__ B2,
    float* __restrict__ E2, float* __restrict__ AGG, float* __restrict__ S2, int e)
{
    int i = blockIdx.x * blockDim.x + threadIdx.x;
    if (i >= e) return;
    float x0 = EF[i];
    int s = SRC[i], d = DST[i];
    float h_s = H1[s], h_d = H1[d];
    float o = B2[0];
    for (int j = 0; j < 64; ++j) {
        float aj = fmaf(x0, W1[j], fmaf(h_s, W1[64+j], fmaf(h_d, W1[128+j], B1[j])));
        o = fmaf(fmaxf(aj, 0.f), W2[j], o);
    }
    float eh = fmaxf(o, 0.f);
    float ex = __expf(eh);
    E2[i] = ex;
    atomAddF(&AGG[d], eh);
    atomAddF(&S2[d], ex);
}

__global__ void k_nu(const float* __restrict__ AGG, const float* __restrict__ H1,
                     const float* __restrict__ W1, const float* __restrict__ B1,
                     const float* __restrict__ W2, const float* __restrict__ B2,
                     float* __restrict__ H2, int n)
{
    int i = blockIdx.x * blockDim.x + threadIdx.x;
    if (i >= n) return;
    float x0 = AGG[i], x1 = H1[i];
    float o = B2[0];
    #pragma unroll
    for (int j = 0; j < 64; ++j) {
        float a = fmaf(x0, W1[j], fmaf(x1, W1[64 + j], B1[j]));
        o = fmaf(fmaxf(a, 0.f), W2[j], o);
    }
    H2[i] = fmaxf(o, 0.f);
}

__global__ void __launch_bounds__(256) k_agg2F(
    const float* __restrict__ E2, const int* __restrict__ SRC,
    const int* __restrict__ DST, const float* __restrict__ H2,
    float* __restrict__ NUM2, int e)
{
    int i = blockIdx.x * blockDim.x + threadIdx.x;
    if (i >= e) return;
    atomAddF(&NUM2[DST[i]], E2[i] * H2[SRC[i]]);
}

__global__ void k_final(const float* __restrict__ NUM2, const float* __restrict__ S2,
                        const float* __restrict__ W1, const float* __restrict__ B1,
                        const float* __restrict__ W2, const float* __restrict__ B2,
                        float* __restrict__ OUT, int n)
{
    int i = blockIdx.x * blockDim.x + threadIdx.x;
    if (i >= n) return;
    float s = S2[i];
    float x = (s != 0.f) ? NUM2[i] / s : 0.f;
    float o = B2[0];
    #pragma unroll
    for (int j = 0; j < 64; ++j) {
        float a = fmaf(x, W1[j], B1[j]);
        o = fmaf(fmaxf(a, 0.f), W2[j], o);
    }
    OUT[i] = fmaxf(o, 0.f);
}

// ============================ launch =======================================

extern "C" void kernel_launch(void* const* d_in, const int* in_sizes, int n_in,
                              void* d_out, int out_size, void* d_ws, size_t ws_size,
                              hipStream_t stream)
{
    const float* node_feat = (const float*)d_in[0];
    const float* edge_feat = (const float*)d_in[1];
    const float* edge_dist = (const float*)d_in[2];
    const int*   src       = (const int*)d_in[3];
    const int*   dst       = (const int*)d_in[4];
    const float* enc_w1 = (const float*)d_in[5];
    const float* enc_b1 = (const float*)d_in[6];
    const float* enc_w2 = (const float*)d_in[7];
    const float* enc_b2 = (const float*)d_in[8];
    const float* nu_w1  = (const float*)d_in[9];
    const float* nu_b1  = (const float*)d_in[10];
    const float* nu_w2  = (const float*)d_in[11];
    const float* nu_b2  = (const float*)d_in[12];
    const float* eu_w1  = (const float*)d_in[13];
    const float* eu_b1  = (const float*)d_in[14];
    const float* eu_w2  = (const float*)d_in[15];
    const float* eu_b2  = (const float*)d_in[16];
    const float* dec_w1 = (const float*)d_in[17];
    const float* dec_b1 = (const float*)d_in[18];
    const float* dec_w2 = (const float*)d_in[19];
    const float* dec_b2 = (const float*)d_in[20];

    const int n = in_sizes[0] / 128;
    const int e = in_sizes[1];
    const int B = 256;

    // shift=9: scatter-side optimum (r14: shift=8 -> 335MB write-amp).
    int shift = 9;
    while ((((n + (1 << shift) - 1) >> shift) > 512) && shift < 12) shift++;
    const int nbkt = (n + (1 << shift) - 1) >> shift;
    int epb = (e + NHB - 1) / NHB;
    epb = (epb + 3) & ~3;

    // ws layout (4B words): h0,h1,h2,s2 [4n] | base[nbkt+1] bktCnt[nbkt]
    // hist[nbkt*NHB] | pad8 | payA[2e] | ef_s[e] | pP0 | pP1
    float* ws = (float*)d_ws;
    size_t w = (size_t)4 * n;
    int* base   = (int*)(ws + w); w += nbkt + 1;
    int* bktCnt = (int*)(ws + w); w += nbkt;
    int* hist   = (int*)(ws + w); w += (size_t)nbkt * NHB;
    w = (w + 1) & ~(size_t)1;
    float2* payA = (float2*)(ws + w); w += (size_t)2 * e;
    float* ef_s  = ws + w; w += e;

    // pick largest G in {16,8,4,2,1} whose partial arrays fit the workspace
    int G = 16;
    size_t psz;
    size_t need;
    for (;;) {
        psz = ((size_t)nbkt * G) << shift;
        need = (w + 2 * psz) * 4;
        if (need <= ws_size || G == 1) break;
        G >>= 1;
    }
    float* pP0 = ws + w;
    float* pP1 = ws + w + psz;

    float* h0 = ws;
    float* h1 = ws + (size_t)1 * n;
    float* h2 = ws + (size_t)2 * n;
    float* s2 = ws + (size_t)3 * n;

    if (ws_size >= need && nbkt <= 512 && (1 << shift) <= 512 &&
        ((size_t)n << shift) < (1u << 30)) {
        const int gE = nbkt * G;
        hipLaunchKernelGGL(k_encchist, dim3(NHB), dim3(1024), 0, stream,
                           node_feat, enc_w1, enc_b1, enc_w2, enc_b2, h0, n,
                           dst, hist, e, nbkt, shift, epb);
        hipLaunchKernelGGL(k_scanA, dim3(nbkt), dim3(B), 0, stream, hist, bktCnt);
        hipLaunchKernelGGL(k_scanB, dim3(1), dim3(B), 0, stream, bktCnt, base, nbkt, e);
        hipLaunchKernelGGL(k_scatter, dim3(NHB), dim3(1024), 0, stream,
                           dst, src, edge_dist, edge_feat, hist, base,
                           payA, ef_s, e, nbkt, shift, epb);
        hipLaunchKernelGGL(k_passA, dim3(gE), dim3(B), 0, stream,
                           payA, h0, base, pP0, pP1, shift, G);
        hipLaunchKernelGGL(k_finA, dim3((n + B - 1) / B), dim3(B), 0, stream,
                           pP0, pP1, h1, shift, n, G);
        hipLaunchKernelGGL(k_passB, dim3(gE), dim3(B), 0, stream,
                           payA, ef_s, h1, eu_w1, eu_b1, eu_w2, eu_b2, base,
                           pP0, pP1, shift, n, G);
        hipLaunchKernelGGL(k_finB, dim3((n + B - 1) / B), dim3(B), 0, stream,
                           pP0, pP1, h1, nu_w1, nu_b1, nu_w2, nu_b2, h2, s2,
                           shift, n, G);
        hipLaunchKernelGGL(k_passC, dim3(gE), dim3(B), 0, stream,
                           payA, h2, base, pP0, shift, G);
        hipLaunchKernelGGL(k_finC, dim3((n + B - 1) / B), dim3(B), 0, stream,
                           pP0, s2, dec_w1, dec_b1, dec_w2, dec_b2,
                           (float*)d_out, shift, n, G);
    } else {
        // fallback: atomic path (needs 8n + e floats)
        float* agg  = ws + (size_t)2 * n;
        float* s1   = ws + (size_t)4 * n;
        float* num1 = ws + (size_t)5 * n;
        float* num2 = ws + (size_t)6 * n;
        float* h2f  = ws + (size_t)7 * n;
        float* e2   = ws + (size_t)8 * n;
        hipLaunchKernelGGL(k_zero, dim3((5 * n + B - 1) / B), dim3(B), 0, stream,
                           agg, 5 * n);
        hipLaunchKernelGGL(k_enc, dim3((n + B - 1) / B), dim3(B), 0, stream,
                           node_feat, enc_w1, enc_b1, enc_w2, enc_b2, h0, n);
        hipLaunchKernelGGL(k_agg1, dim3((e + B - 1) / B), dim3(B), 0, stream,
                           edge_dist, src, dst, h0, s1, num1, e);
        hipLaunchKernelGGL(k_div, dim3((n + B - 1) / B), dim3(B), 0, stream,
                           num1, s1, h1, n);
        hipLaunchKernelGGL(k_edgeF, dim3((e + B - 1) / B), dim3(B), 0, stream,
                           edge_feat, src, dst, h1, eu_w1, eu_b1, eu_w2, eu_b2,
                           e2, agg, s2, e);
        hipLaunchKernelGGL(k_nu, dim3((n + B - 1) / B), dim3(B), 0, stream,
                           agg, h1, nu_w1, nu_b1, nu_w2, nu_b2, h2f, n);
        hipLaunchKernelGGL(k_agg2F, dim3((e + B - 1) / B), dim3(B), 0, stream,
                           e2, src, dst, h2f, num2, e);
        hipLaunchKernelGGL(k_final, dim3((n + B - 1) / B), dim3(B), 0, stream,
                           num2, s2, dec_w1, dec_b1, dec_w2, dec_b2, (float*)d_out, n);
    }
}

// Round 19
// 376.391 us; speedup vs baseline: 1.0933x; 1.0933x over previous
//
#include <hip/hip_runtime.h>

// ---------------------------------------------------------------------------
// GraphElementNetwork forward, bucketed path (FINAL = r17 best, 377.7us):
//  - coarse dst-bucketing (shift=9, ~196 buckets) -> all segment reductions
//    via CU-local LDS bins (r1: fabric atomics = 20G/s wall, 1659us).
//  - NHB=512 x 1024-thr scatter/chist; nontemporal streaming reads; shift=9
//    keeps open write-line set < L2 (r6/r14: narrower buckets -> 4.4x amp).
//  - G<=16 slices/bucket -> per-(bucket,slice) partials + per-node finalize
//    kernels carrying the folded node MLPs (r4: occupancy; r6: VGPR).
//  - edge-MLP weights as wave-uniform scalar (SGPR) loads (r5/r6 lessons:
//    VGPR-hoist = 216 regs; launch_bounds clamp = spill catastrophe).
//  - packed 2xfp32 MLP; exp(dist) precomputed in scatter; e2 written
//    in-place into payA.y -> passC reads one contiguous float2 stream.
//  - passB floor: 102us across 7 structural variants (r10-r17).
//  - r18 lesson: do NOT fuse enc into chist (fat-register phase poisons
//    the memory kernel's occupancy: 378 -> 411us).
// ---------------------------------------------------------------------------

#define NHB 512   // histogram / scatter blocks (2 per CU)

typedef int   iv4 __attribute__((ext_vector_type(4)));
typedef float fv4 __attribute__((ext_vector_type(4)));
typedef float fv2 __attribute__((ext_vector_type(2)));

#if __has_builtin(__builtin_elementwise_fma)
#define FMA2(a, b, c) __builtin_elementwise_fma((a), (b), (c))
#else
static __device__ __forceinline__ fv2 FMA2(fv2 a, fv2 b, fv2 c) {
    fv2 r; r.x = fmaf(a.x, b.x, c.x); r.y = fmaf(a.y, b.y, c.y); return r;
}
#endif
#if __has_builtin(__builtin_elementwise_max)
#define MAX2(a, b) __builtin_elementwise_max((a), (b))
#else
static __device__ __forceinline__ fv2 MAX2(fv2 a, fv2 b) {
    fv2 r; r.x = fmaxf(a.x, b.x); r.y = fmaxf(a.y, b.y); return r;
}
#endif

// ============================ bucketing ====================================

__global__ void __launch_bounds__(1024) k_chist(
    const int* __restrict__ DST, int* __restrict__ hist,
    int e, int nbkt, int shift, int epb)
{
    __shared__ int lh[512];
    for (int c = threadIdx.x; c < nbkt; c += blockDim.x) lh[c] = 0;
    __syncthreads();
    int b = blockIdx.x;
    int i0 = b * epb, i1 = min(i0 + epb, e);
    int nq = (i1 > i0) ? ((i1 - i0) >> 2) : 0;
    const iv4* D4 = reinterpret_cast<const iv4*>(DST + i0);
    for (int q = threadIdx.x; q < nq; q += blockDim.x) {
        iv4 d = D4[q];
        atomicAdd(&lh[d.x >> shift], 1);
        atomicAdd(&lh[d.y >> shift], 1);
        atomicAdd(&lh[d.z >> shift], 1);
        atomicAdd(&lh[d.w >> shift], 1);
    }
    for (int i = i0 + 4 * nq + threadIdx.x; i < i1; i += blockDim.x)
        atomicAdd(&lh[DST[i] >> shift], 1);
    __syncthreads();
    for (int c = threadIdx.x; c < nbkt; c += blockDim.x)
        hist[(size_t)c * NHB + b] = lh[c];
}

// exclusive scan of each bucket's NHB=512 per-block counts (2 elems/thread)
__global__ void __launch_bounds__(256) k_scanA(
    int* __restrict__ hist, int* __restrict__ bktCnt)
{
    int c = blockIdx.x;
    int* row = hist + (size_t)c * NHB;
    __shared__ int part[256];
    int t = threadIdx.x;
    int a = row[2 * t];
    int bv = row[2 * t + 1];
    part[t] = a + bv;
    __syncthreads();
    for (int off = 1; off < 256; off <<= 1) {
        int x = 0;
        if (t >= off) x = part[t - off];
        __syncthreads();
        part[t] += x;
        __syncthreads();
    }
    if (t == 255) bktCnt[c] = part[255];
    int run = (t == 0) ? 0 : part[t - 1];
    row[2 * t] = run;
    row[2 * t + 1] = run + a;
}

__global__ void __launch_bounds__(256) k_scanB(
    const int* __restrict__ bktCnt, int* __restrict__ base, int nbkt, int e)
{
    __shared__ int part[256];
    int t = threadIdx.x;
    int v[4];
    int sum = 0;
    #pragma unroll
    for (int u = 0; u < 4; ++u) {
        int idx = t * 4 + u;
        v[u] = (idx < nbkt) ? bktCnt[idx] : 0;
        sum += v[u];
    }
    part[t] = sum;
    __syncthreads();
    for (int off = 1; off < 256; off <<= 1) {
        int x = 0;
        if (t >= off) x = part[t - off];
        __syncthreads();
        part[t] += x;
        __syncthreads();
    }
    int run = (t == 0) ? 0 : part[t - 1];
    #pragma unroll
    for (int u = 0; u < 4; ++u) {
        int idx = t * 4 + u;
        if (idx < nbkt) base[idx] = run;
        run += v[u];
    }
    if (t == 0) base[nbkt] = e;
}

// scatter: payA[pos] = (sd, exp(dist)); ef_s[pos] = ef
__global__ void __launch_bounds__(1024) k_scatter(
    const int* __restrict__ DST, const int* __restrict__ SRC,
    const float* __restrict__ DIST, const float* __restrict__ EF,
    const int* __restrict__ hist, const int* __restrict__ base,
    float2* __restrict__ payA, float* __restrict__ ef_s,
    int e, int nbkt, int shift, int epb)
{
    __shared__ int loff[512];
    int b = blockIdx.x;
    for (int c = threadIdx.x; c < nbkt; c += blockDim.x)
        loff[c] = base[c] + hist[(size_t)c * NHB + b];
    __syncthreads();
    int i0 = b * epb, i1 = min(i0 + epb, e);
    if (i0 >= i1) return;
    int mask = (1 << shift) - 1;
    int nq = (i1 - i0) >> 2;
    const iv4* D4 = reinterpret_cast<const iv4*>(DST + i0);
    const iv4* S4 = reinterpret_cast<const iv4*>(SRC + i0);
    const fv4* T4 = reinterpret_cast<const fv4*>(DIST + i0);
    const fv4* F4 = reinterpret_cast<const fv4*>(EF + i0);
    for (int q = threadIdx.x; q < nq; q += blockDim.x) {
        iv4 dv = __builtin_nontemporal_load(D4 + q);
        iv4 sv = __builtin_nontemporal_load(S4 + q);
        fv4 tv = __builtin_nontemporal_load(T4 + q);
        fv4 fv = __builtin_nontemporal_load(F4 + q);
        #pragma unroll
        for (int u = 0; u < 4; ++u) {
            int d = dv[u];
            int c = d >> shift;
            int pos = atomicAdd(&loff[c], 1);
            int sd = (sv[u] << shift) | (d & mask);
            payA[pos] = make_float2(__int_as_float(sd), __expf(tv[u]));
            ef_s[pos] = fv[u];
        }
    }
    for (int i = i0 + 4 * nq + threadIdx.x; i < i1; i += blockDim.x) {
        int d = DST[i];
        int c = d >> shift;
        int pos = atomicAdd(&loff[c], 1);
        int sd = (SRC[i] << shift) | (d & mask);
        payA[pos] = make_float2(__int_as_float(sd), __expf(DIST[i]));
        ef_s[pos] = EF[i];
    }
}

// ============================ node encoder =================================

__global__ void __launch_bounds__(256) k_enc(
    const float* __restrict__ X, const float* __restrict__ W1,
    const float* __restrict__ B1, const float* __restrict__ W2,
    const float* __restrict__ B2, float* __restrict__ H0, int n)
{
    __shared__ float4 w1s[2048];
    for (int t = threadIdx.x; t < 2048; t += blockDim.x)
        w1s[t] = reinterpret_cast<const float4*>(W1)[t];
    __syncthreads();

    int i = blockIdx.x * blockDim.x + threadIdx.x;
    if (i >= n) return;

    const float4* xp = reinterpret_cast<const float4*>(X) + (size_t)i * 32;

    float acc[64];
    #pragma unroll
    for (int j = 0; j < 64; ++j) acc[j] = B1[j];

    for (int k4 = 0; k4 < 32; ++k4) {
        float4 xv = xp[k4];
        #pragma unroll
        for (int kk = 0; kk < 4; ++kk) {
            float x = (&xv.x)[kk];
            const float4* wrow = &w1s[(k4 * 4 + kk) * 16];
            #pragma unroll
            for (int j4 = 0; j4 < 16; ++j4) {
                float4 w = wrow[j4];
                acc[j4*4+0] = fmaf(x, w.x, acc[j4*4+0]);
                acc[j4*4+1] = fmaf(x, w.y, acc[j4*4+1]);
                acc[j4*4+2] = fmaf(x, w.z, acc[j4*4+2]);
                acc[j4*4+3] = fmaf(x, w.w, acc[j4*4+3]);
            }
        }
    }
    float o = B2[0];
    #pragma unroll
    for (int j = 0; j < 64; ++j)
        o = fmaf(fmaxf(acc[j], 0.f), W2[j], o);
    H0[i] = fmaxf(o, 0.f);
}

// ==================== bucketed edge passes (G-split) =======================
// partial layout: p[((c*G + g) << shift) + t]

__global__ void __launch_bounds__(256) k_passA(
    const float2* __restrict__ payA, const float* __restrict__ H0,
    const int* __restrict__ base,
    float* __restrict__ pSum, float* __restrict__ pNum, int shift, int G)
{
    __shared__ float lsum[512], lnum[512];
    int c = blockIdx.x / G, g = blockIdx.x % G;
    int bw = 1 << shift, mask = bw - 1;
    for (int t = threadIdx.x; t < bw; t += blockDim.x) { lsum[t] = 0.f; lnum[t] = 0.f; }
    __syncthreads();
    int b0 = base[c], len = base[c + 1] - b0;
    int i0 = b0 + (int)(((long long)len * g) / G);
    int i1 = b0 + (int)(((long long)len * (g + 1)) / G);
    const int T = blockDim.x;
    for (int i = i0 + (int)threadIdx.x; i < i1; i += 4 * T) {
        fv2 p[4]; bool v[4]; int sd[4]; float h[4];
        #pragma unroll
        for (int u = 0; u < 4; ++u) {
            int j = i + u * T;
            v[u] = j < i1;
            p[u].x = 0.f; p[u].y = 0.f;
            if (v[u]) p[u] = __builtin_nontemporal_load(
                          reinterpret_cast<const fv2*>(payA) + j);
        }
        #pragma unroll
        for (int u = 0; u < 4; ++u) {
            sd[u] = __float_as_int(p[u].x);
            h[u] = v[u] ? H0[sd[u] >> shift] : 0.f;
        }
        #pragma unroll
        for (int u = 0; u < 4; ++u) {
            if (v[u]) {
                atomicAdd(&lsum[sd[u] & mask], p[u].y);          // exp(dist)
                atomicAdd(&lnum[sd[u] & mask], p[u].y * h[u]);
            }
        }
    }
    __syncthreads();
    size_t po = (size_t)blockIdx.x << shift;
    for (int t = threadIdx.x; t < bw; t += blockDim.x) {
        pSum[po + t] = lsum[t];
        pNum[po + t] = lnum[t];
    }
}

__global__ void __launch_bounds__(256) k_finA(
    const float* __restrict__ pSum, const float* __restrict__ pNum,
    float* __restrict__ H1, int shift, int n, int G)
{
    int d = blockIdx.x * blockDim.x + threadIdx.x;
    if (d >= n) return;
    int c = d >> shift, t = d & ((1 << shift) - 1);
    size_t b = (size_t)c * G << shift;
    int bw = 1 << shift;
    float s = 0.f, m = 0.f;
    for (int g = 0; g < G; ++g) {
        s += pSum[b + (size_t)g * bw + t];
        m += pNum[b + (size_t)g * bw + t];
    }
    H1[d] = (s != 0.f) ? m / s : 0.f;
}

// passB main: edge MLP; writes e2 into payA[j].y (in-place, exp(dist) dead
// after passA); partial agg/s2 into LDS bins.
__global__ void __launch_bounds__(256) k_passB(
    float2* __restrict__ payA, const float* __restrict__ ef_s,
    const float* __restrict__ H1,
    const float* __restrict__ W1, const float* __restrict__ B1,
    const float* __restrict__ W2, const float* __restrict__ B2,
    const int* __restrict__ base,
    float* __restrict__ pAgg, float* __restrict__ pS2, int shift, int n, int G)
{
    __shared__ float h1loc[512], lagg[512], ls2[512];
    const fv2 ZERO2 = {0.f, 0.f};
    int bw = 1 << shift, mask = bw - 1;
    int c = blockIdx.x / G, g = blockIdx.x % G;
    int d0 = c << shift;
    for (int t = threadIdx.x; t < bw; t += blockDim.x) {
        int d = d0 + t;
        h1loc[t] = (d < n) ? H1[d] : 0.f;
        lagg[t] = 0.f;
        ls2[t] = 0.f;
    }
    __syncthreads();
    const float b2 = B2[0];
    int b0 = base[c], len = base[c + 1] - b0;
    int i0 = b0 + (int)(((long long)len * g) / G);
    int i1 = b0 + (int)(((long long)len * (g + 1)) / G);
    const int T = blockDim.x;

    int i = i0 + (int)threadIdx.x;
    fv2 pa[4]; float xf[4];
    #pragma unroll
    for (int u = 0; u < 4; ++u) {
        int j = i + u * T;
        pa[u] = ZERO2; xf[u] = 0.f;
        if (j < i1) {
            pa[u] = __builtin_nontemporal_load(
                reinterpret_cast<const fv2*>(payA) + j);
            xf[u] = __builtin_nontemporal_load(ef_s + j);
        }
    }
    float* payF = reinterpret_cast<float*>(payA);
    while (i < i1) {
        int inext = i + 4 * T;
        // prefetch next chunk BEFORE the store/atomic phase of this chunk
        fv2 pb[4]; float xg[4];
        #pragma unroll
        for (int u = 0; u < 4; ++u) {
            int j = inext + u * T;
            pb[u] = ZERO2; xg[u] = 0.f;
            if (j < i1) {
                pb[u] = __builtin_nontemporal_load(
                    reinterpret_cast<const fv2*>(payA) + j);
                xg[u] = __builtin_nontemporal_load(ef_s + j);
            }
        }
        // gathers + packed MLP
        fv2 x0v[4], hsv[4], hdv[4], o2[4];
        int lo[4];
        #pragma unroll
        for (int u = 0; u < 4; ++u) {
            int sd = __float_as_int(pa[u].x);
            lo[u] = sd & mask;
            float hs = H1[sd >> shift];
            float hd = h1loc[lo[u]];
            fv2 xt; xt.x = xf[u]; xt.y = xf[u];
            x0v[u] = xt;
            fv2 ht; ht.x = hs; ht.y = hs;
            hsv[u] = ht;
            fv2 dt; dt.x = hd; dt.y = hd;
            hdv[u] = dt;
            o2[u] = ZERO2;
        }
        #pragma unroll 4
        for (int j = 0; j < 64; j += 2) {
            fv2 aj = *reinterpret_cast<const fv2*>(W1 + j);
            fv2 bj = *reinterpret_cast<const fv2*>(W1 + 64 + j);
            fv2 cj = *reinterpret_cast<const fv2*>(W1 + 128 + j);
            fv2 dj = *reinterpret_cast<const fv2*>(B1 + j);
            fv2 vj = *reinterpret_cast<const fv2*>(W2 + j);
            #pragma unroll
            for (int u = 0; u < 4; ++u) {
                fv2 t = FMA2(x0v[u], aj,
                         FMA2(hsv[u], bj, FMA2(hdv[u], cj, dj)));
                t = MAX2(t, ZERO2);
                o2[u] = FMA2(t, vj, o2[u]);
            }
        }
        #pragma unroll
        for (int u = 0; u < 4; ++u) {
            int j = i + u * T;
            if (j < i1) {
                float eh = fmaxf(o2[u].x + o2[u].y + b2, 0.f);
                float ex = __expf(eh);
                payF[2 * j + 1] = ex;   // e2 -> payA[j].y
                atomicAdd(&lagg[lo[u]], eh);
                atomicAdd(&ls2[lo[u]], ex);
            }
        }
        i = inext;
        #pragma unroll
        for (int u = 0; u < 4; ++u) { pa[u] = pb[u]; xf[u] = xg[u]; }
    }
    __syncthreads();
    size_t po = (size_t)blockIdx.x << shift;
    for (int t = threadIdx.x; t < bw; t += blockDim.x) {
        pAgg[po + t] = lagg[t];
        pS2[po + t] = ls2[t];
    }
}

// finB: sum partials; H2 = nuMLP(agg, h1); S2
__global__ void __launch_bounds__(256) k_finB(
    const float* __restrict__ pAgg, const float* __restrict__ pS2,
    const float* __restrict__ H1,
    const float* __restrict__ NW1, const float* __restrict__ NB1,
    const float* __restrict__ NW2, const float* __restrict__ NB2,
    float* __restrict__ H2, float* __restrict__ S2, int shift, int n, int G)
{
    int d = blockIdx.x * blockDim.x + threadIdx.x;
    if (d >= n) return;
    int c = d >> shift, t = d & ((1 << shift) - 1);
    size_t b = (size_t)c * G << shift;
    int bw = 1 << shift;
    float agg = 0.f, s2 = 0.f;
    for (int g = 0; g < G; ++g) {
        agg += pAgg[b + (size_t)g * bw + t];
        s2  += pS2[b + (size_t)g * bw + t];
    }
    float xh = H1[d];
    float o = NB2[0];
    #pragma unroll 4
    for (int j = 0; j < 64; ++j) {
        float a = fmaf(agg, NW1[j], fmaf(xh, NW1[64 + j], NB1[j]));
        o = fmaf(fmaxf(a, 0.f), NW2[j], o);
    }
    H2[d] = fmaxf(o, 0.f);
    S2[d] = s2;
}

// passC main: partial num2. Single contiguous stream: payA[j] = (sd, e2).
__global__ void __launch_bounds__(256) k_passC(
    const float2* __restrict__ payA,
    const float* __restrict__ H2, const int* __restrict__ base,
    float* __restrict__ pNum, int shift, int G)
{
    __shared__ float lnum[512];
    int c = blockIdx.x / G, g = blockIdx.x % G;
    int bw = 1 << shift, mask = bw - 1;
    for (int t = threadIdx.x; t < bw; t += blockDim.x) lnum[t] = 0.f;
    __syncthreads();
    int b0 = base[c], len = base[c + 1] - b0;
    int i0 = b0 + (int)(((long long)len * g) / G);
    int i1 = b0 + (int)(((long long)len * (g + 1)) / G);
    const int T = blockDim.x;
    for (int i = i0 + (int)threadIdx.x; i < i1; i += 4 * T) {
        fv2 p[4]; bool v[4]; int sd[4]; float h[4];
        #pragma unroll
        for (int u = 0; u < 4; ++u) {
            int j = i + u * T;
            v[u] = j < i1;
            p[u].x = 0.f; p[u].y = 0.f;
            if (v[u]) p[u] = __builtin_nontemporal_load(
                          reinterpret_cast<const fv2*>(payA) + j);
        }
        #pragma unroll
        for (int u = 0; u < 4; ++u) {
            sd[u] = __float_as_int(p[u].x);
            h[u] = v[u] ? H2[sd[u] >> shift] : 0.f;
        }
        #pragma unroll
        for (int u = 0; u < 4; ++u) {
            if (v[u]) atomicAdd(&lnum[sd[u] & mask], p[u].y * h[u]);
        }
    }
    __syncthreads();
    size_t po = (size_t)blockIdx.x << shift;
    for (int t = threadIdx.x; t < bw; t += blockDim.x)
        pNum[po + t] = lnum[t];
}

// finC: sum partials; OUT = decMLP(num2/s2)
__global__ void __launch_bounds__(256) k_finC(
    const float* __restrict__ pNum, const float* __restrict__ S2,
    const float* __restrict__ W1, const float* __restrict__ B1,
    const float* __restrict__ W2, const float* __restrict__ B2,
    float* __restrict__ OUT, int shift, int n, int G)
{
    int d = blockIdx.x * blockDim.x + threadIdx.x;
    if (d >= n) return;
    int c = d >> shift, t = d & ((1 << shift) - 1);
    size_t b = (size_t)c * G << shift;
    int bw = 1 << shift;
    float m = 0.f;
    for (int g = 0; g < G; ++g) m += pNum[b + (size_t)g * bw + t];
    float s = S2[d];
    float x = (s != 0.f) ? m / s : 0.f;
    float o = B2[0];
    #pragma unroll 4
    for (int j = 0; j < 64; ++j) {
        float a = fmaf(x, W1[j], B1[j]);
        o = fmaf(fmaxf(a, 0.f), W2[j], o);
    }
    OUT[d] = fmaxf(o, 0.f);
}

// ===================== fallback (atomic path) ==============================

__device__ __forceinline__ void atomAddF(float* p, float v) { unsafeAtomicAdd(p, v); }

__global__ void k_zero(float* __restrict__ p, int n) {
    int i = blockIdx.x * blockDim.x + threadIdx.x;
    if (i < n) p[i] = 0.f;
}

__global__ void __launch_bounds__(256) k_agg1(
    const float* __restrict__ DIST, const int* __restrict__ SRC,
    const int* __restrict__ DST, const float* __restrict__ H0,
    float* __restrict__ S1, float* __restrict__ NUM1, int e)
{
    int i = blockIdx.x * blockDim.x + threadIdx.x;
    if (i >= e) return;
    float ev = __expf(DIST[i]);
    atomAddF(&S1[DST[i]], ev);
    atomAddF(&NUM1[DST[i]], ev * H0[SRC[i]]);
}

__global__ void k_div(const float* __restrict__ NUM, const float* __restrict__ S,
                      float* __restrict__ H, int n) {
    int i = blockIdx.x * blockDim.x + threadIdx.x;
    if (i < n) {
        float s = S[i];
        H[i] = (s != 0.f) ? NUM[i] / s : 0.f;
    }
}

__global__ void __launch_bounds__(256) k_edgeF(
    const float* __restrict__ EF, const int* __restrict__ SRC,
    const int* __restrict__ DST, const float* __restrict__ H1,
    const float* __restrict__ W1, const float* __restrict__ B1,
    const float* __restrict__ W2, const float* __restrict__ B2,
    float* __restrict__ E2, float* __restrict__ AGG, float* __restrict__ S2, int e)
{
    int i = blockIdx.x * blockDim.x + threadIdx.x;
    if (i >= e) return;
    float x0 = EF[i];
    int s = SRC[i], d = DST[i];
    float h_s = H1[s], h_d = H1[d];
    float o = B2[0];
    for (int j = 0; j < 64; ++j) {
        float aj = fmaf(x0, W1[j], fmaf(h_s, W1[64+j], fmaf(h_d, W1[128+j], B1[j])));
        o = fmaf(fmaxf(aj, 0.f), W2[j], o);
    }
    float eh = fmaxf(o, 0.f);
    float ex = __expf(eh);
    E2[i] = ex;
    atomAddF(&AGG[d], eh);
    atomAddF(&S2[d], ex);
}

__global__ void k_nu(const float* __restrict__ AGG, const float* __restrict__ H1,
                     const float* __restrict__ W1, const float* __restrict__ B1,
                     const float* __restrict__ W2, const float* __restrict__ B2,
                     float* __restrict__ H2, int n)
{
    int i = blockIdx.x * blockDim.x + threadIdx.x;
    if (i >= n) return;
    float x0 = AGG[i], x1 = H1[i];
    float o = B2[0];
    #pragma unroll
    for (int j = 0; j < 64; ++j) {
        float a = fmaf(x0, W1[j], fmaf(x1, W1[64 + j], B1[j]));
        o = fmaf(fmaxf(a, 0.f), W2[j], o);
    }
    H2[i] = fmaxf(o, 0.f);
}

__global__ void __launch_bounds__(256) k_agg2F(
    const float* __restrict__ E2, const int* __restrict__ SRC,
    const int* __restrict__ DST, const float* __restrict__ H2,
    float* __restrict__ NUM2, int e)
{
    int i = blockIdx.x * blockDim.x + threadIdx.x;
    if (i >= e) return;
    atomAddF(&NUM2[DST[i]], E2[i] * H2[SRC[i]]);
}

__global__ void k_final(const float* __restrict__ NUM2, const float* __restrict__ S2,
                        const float* __restrict__ W1, const float* __restrict__ B1,
                        const float* __restrict__ W2, const float* __restrict__ B2,
                        float* __restrict__ OUT, int n)
{
    int i = blockIdx.x * blockDim.x + threadIdx.x;
    if (i >= n) return;
    float s = S2[i];
    float x = (s != 0.f) ? NUM2[i] / s : 0.f;
    float o = B2[0];
    #pragma unroll
    for (int j = 0; j < 64; ++j) {
        float a = fmaf(x, W1[j], B1[j]);
        o = fmaf(fmaxf(a, 0.f), W2[j], o);
    }
    OUT[i] = fmaxf(o, 0.f);
}

// ============================ launch =======================================

extern "C" void kernel_launch(void* const* d_in, const int* in_sizes, int n_in,
                              void* d_out, int out_size, void* d_ws, size_t ws_size,
                              hipStream_t stream)
{
    const float* node_feat = (const float*)d_in[0];
    const float* edge_feat = (const float*)d_in[1];
    const float* edge_dist = (const float*)d_in[2];
    const int*   src       = (const int*)d_in[3];
    const int*   dst       = (const int*)d_in[4];
    const float* enc_w1 = (const float*)d_in[5];
    const float* enc_b1 = (const float*)d_in[6];
    const float* enc_w2 = (const float*)d_in[7];
    const float* enc_b2 = (const float*)d_in[8];
    const float* nu_w1  = (const float*)d_in[9];
    const float* nu_b1  = (const float*)d_in[10];
    const float* nu_w2  = (const float*)d_in[11];
    const float* nu_b2  = (const float*)d_in[12];
    const float* eu_w1  = (const float*)d_in[13];
    const float* eu_b1  = (const float*)d_in[14];
    const float* eu_w2  = (const float*)d_in[15];
    const float* eu_b2  = (const float*)d_in[16];
    const float* dec_w1 = (const float*)d_in[17];
    const float* dec_b1 = (const float*)d_in[18];
    const float* dec_w2 = (const float*)d_in[19];
    const float* dec_b2 = (const float*)d_in[20];

    const int n = in_sizes[0] / 128;
    const int e = in_sizes[1];
    const int B = 256;

    // shift=9: scatter-side optimum (r14: shift=8 -> 335MB write-amp).
    int shift = 9;
    while ((((n + (1 << shift) - 1) >> shift) > 512) && shift < 12) shift++;
    const int nbkt = (n + (1 << shift) - 1) >> shift;
    int epb = (e + NHB - 1) / NHB;
    epb = (epb + 3) & ~3;

    // ws layout (4B words): h0,h1,h2,s2 [4n] | base[nbkt+1] bktCnt[nbkt]
    // hist[nbkt*NHB] | pad8 | payA[2e] | ef_s[e] | pP0 | pP1
    float* ws = (float*)d_ws;
    size_t w = (size_t)4 * n;
    int* base   = (int*)(ws + w); w += nbkt + 1;
    int* bktCnt = (int*)(ws + w); w += nbkt;
    int* hist   = (int*)(ws + w); w += (size_t)nbkt * NHB;
    w = (w + 1) & ~(size_t)1;
    float2* payA = (float2*)(ws + w); w += (size_t)2 * e;
    float* ef_s  = ws + w; w += e;

    // pick largest G in {16,8,4,2,1} whose partial arrays fit the workspace
    int G = 16;
    size_t psz;
    size_t need;
    for (;;) {
        psz = ((size_t)nbkt * G) << shift;
        need = (w + 2 * psz) * 4;
        if (need <= ws_size || G == 1) break;
        G >>= 1;
    }
    float* pP0 = ws + w;
    float* pP1 = ws + w + psz;

    float* h0 = ws;
    float* h1 = ws + (size_t)1 * n;
    float* h2 = ws + (size_t)2 * n;
    float* s2 = ws + (size_t)3 * n;

    if (ws_size >= need && nbkt <= 512 && (1 << shift) <= 512 &&
        ((size_t)n << shift) < (1u << 30)) {
        const int gE = nbkt * G;
        hipLaunchKernelGGL(k_chist, dim3(NHB), dim3(1024), 0, stream,
                           dst, hist, e, nbkt, shift, epb);
        hipLaunchKernelGGL(k_scanA, dim3(nbkt), dim3(B), 0, stream, hist, bktCnt);
        hipLaunchKernelGGL(k_scanB, dim3(1), dim3(B), 0, stream, bktCnt, base, nbkt, e);
        hipLaunchKernelGGL(k_scatter, dim3(NHB), dim3(1024), 0, stream,
                           dst, src, edge_dist, edge_feat, hist, base,
                           payA, ef_s, e, nbkt, shift, epb);
        hipLaunchKernelGGL(k_enc, dim3((n + B - 1) / B), dim3(B), 0, stream,
                           node_feat, enc_w1, enc_b1, enc_w2, enc_b2, h0, n);
        hipLaunchKernelGGL(k_passA, dim3(gE), dim3(B), 0, stream,
                           payA, h0, base, pP0, pP1, shift, G);
        hipLaunchKernelGGL(k_finA, dim3((n + B - 1) / B), dim3(B), 0, stream,
                           pP0, pP1, h1, shift, n, G);
        hipLaunchKernelGGL(k_passB, dim3(gE), dim3(B), 0, stream,
                           payA, ef_s, h1, eu_w1, eu_b1, eu_w2, eu_b2, base,
                           pP0, pP1, shift, n, G);
        hipLaunchKernelGGL(k_finB, dim3((n + B - 1) / B), dim3(B), 0, stream,
                           pP0, pP1, h1, nu_w1, nu_b1, nu_w2, nu_b2, h2, s2,
                           shift, n, G);
        hipLaunchKernelGGL(k_passC, dim3(gE), dim3(B), 0, stream,
                           payA, h2, base, pP0, shift, G);
        hipLaunchKernelGGL(k_finC, dim3((n + B - 1) / B), dim3(B), 0, stream,
                           pP0, s2, dec_w1, dec_b1, dec_w2, dec_b2,
                           (float*)d_out, shift, n, G);
    } else {
        // fallback: atomic path (needs 8n + e floats)
        float* agg  = ws + (size_t)2 * n;
        float* s1   = ws + (size_t)4 * n;
        float* num1 = ws + (size_t)5 * n;
        float* num2 = ws + (size_t)6 * n;
        float* h2f  = ws + (size_t)7 * n;
        float* e2   = ws + (size_t)8 * n;
        hipLaunchKernelGGL(k_zero, dim3((5 * n + B - 1) / B), dim3(B), 0, stream,
                           agg, 5 * n);
        hipLaunchKernelGGL(k_enc, dim3((n + B - 1) / B), dim3(B), 0, stream,
                           node_feat, enc_w1, enc_b1, enc_w2, enc_b2, h0, n);
        hipLaunchKernelGGL(k_agg1, dim3((e + B - 1) / B), dim3(B), 0, stream,
                           edge_dist, src, dst, h0, s1, num1, e);
        hipLaunchKernelGGL(k_div, dim3((n + B - 1) / B), dim3(B), 0, stream,
                           num1, s1, h1, n);
        hipLaunchKernelGGL(k_edgeF, dim3((e + B - 1) / B), dim3(B), 0, stream,
                           edge_feat, src, dst, h1, eu_w1, eu_b1, eu_w2, eu_b2,
                           e2, agg, s2, e);
        hipLaunchKernelGGL(k_nu, dim3((n + B - 1) / B), dim3(B), 0, stream,
                           agg, h1, nu_w1, nu_b1, nu_w2, nu_b2, h2f, n);
        hipLaunchKernelGGL(k_agg2F, dim3((e + B - 1) / B), dim3(B), 0, stream,
                           e2, src, dst, h2f, num2, e);
        hipLaunchKernelGGL(k_final, dim3((n + B - 1) / B), dim3(B), 0, stream,
                           num2, s2, dec_w1, dec_b1, dec_w2, dec_b2, (float*)d_out, n);
    }
}